// Round 18
// baseline (89.546 us; speedup 1.0000x reference)
//
#include <hip/hip_runtime.h>

constexpr int NN = 100000;
constexpr int CH = 128;
constexpr int NE = 625000;
constexpr int NI4 = NE / 4;                        // 156250 int4 groups
constexpr int GEMM_BLOCKS = (NN + 63) / 64;        // 1563 (64 rows/block, 16/wave)
constexpr int BUCKET_BLOCKS = 512;                 // phase-1 bucketing blocks
constexpr int GPB = (NI4 + BUCKET_BLOCKS - 1) / BUCKET_BLOCKS;  // 306 int4/block
constexpr int NB = 196;                            // ceil(NN/512) coarse buckets
constexpr int CAP = 4096;                          // slots/bucket (max ~3390)
constexpr int WCONV_BLOCKS = 16;                   // 16384 elems / 1024

typedef __bf16 bf16x8 __attribute__((ext_vector_type(8)));
typedef __bf16 bf16x4 __attribute__((ext_vector_type(4)));
typedef float  f32x4  __attribute__((ext_vector_type(4)));

__device__ __forceinline__ float bflo(uint u) { return __uint_as_float(u << 16); }
__device__ __forceinline__ float bfhi(uint u) { return __uint_as_float(u & 0xffff0000u); }

// Async 16B global->LDS DMA. LDS dest is wave-uniform base + lane*16.
__device__ __forceinline__ void async_copy16(const void* g, void* l) {
    __builtin_amdgcn_global_load_lds(
        (const __attribute__((address_space(1))) unsigned int*)(uintptr_t)g,
        (__attribute__((address_space(3))) unsigned int*)(uintptr_t)l,
        16, 0, 0);
}

// ---- prep: init bucket cursors + convert W to bf16 swizzled ----
__global__ __launch_bounds__(256) void prep_kernel(
    int* __restrict__ gcursor, const float* __restrict__ W, __bf16* __restrict__ Wb)
{
    if (blockIdx.x == 0) {
        gcursor[threadIdx.x] = threadIdx.x * CAP;
        return;
    }
    int i = (blockIdx.x - 1) * 256 + threadIdx.x;   // float4 group, 4096 total
    int ch = i >> 5;
    int k0 = (i & 31) * 4;
    float4 v = reinterpret_cast<const float4*>(W)[i];
    bf16x4 h = {(__bf16)v.x, (__bf16)v.y, (__bf16)v.z, (__bf16)v.w};
    *reinterpret_cast<bf16x4*>(&Wb[ch * 128 + (k0 ^ ((ch & 7) << 3))]) = h;
}

// ---- fused: coarse bucketing (blocks < BUCKET_BLOCKS) + MFMA GEMM ----
// Bucket: int4 edge loads, (src,dst) register-cached between the two passes;
// per-edge atomics are LDS-only; <=131K global range reservations.
// GEMM: pre-swizzled Wb staged via global_load_lds w=16, 16 rows/wave.
__global__ __launch_bounds__(256) void gemm_bucket_kernel(
    const float* __restrict__ x, const __bf16* __restrict__ Wb,
    const float* __restrict__ b, __bf16* __restrict__ xt,
    const int* __restrict__ ei, int* __restrict__ gcursor, int2* __restrict__ pairs)
{
    __shared__ __bf16 wlds[128 * 128];     // 32 KB; bucket blocks alias it
    const int tid = threadIdx.x;

    if (blockIdx.x < BUCKET_BLOCKS) {
        int* lhist = (int*)wlds;           // [256]
        int* lbase = lhist + 256;          // [256]
        const int4* ei4 = reinterpret_cast<const int4*>(ei);
        const int g0 = blockIdx.x * GPB;
        const int gend = min(g0 + GPB, NI4);
        const int g1 = g0 + tid;
        const int g2 = g1 + 256;
        const bool v1 = g1 < gend;
        const bool v2 = g2 < gend;

        int4 s1 = {0,0,0,0}, d1 = {0,0,0,0}, s2 = {0,0,0,0}, d2 = {0,0,0,0};
        if (v1) { s1 = ei4[g1]; d1 = ei4[NI4 + g1]; }
        if (v2) { s2 = ei4[g2]; d2 = ei4[NI4 + g2]; }

        lhist[tid] = 0;
        __syncthreads();
        if (v1) {
            atomicAdd(&lhist[d1.x >> 9], 1);
            atomicAdd(&lhist[d1.y >> 9], 1);
            atomicAdd(&lhist[d1.z >> 9], 1);
            atomicAdd(&lhist[d1.w >> 9], 1);
        }
        if (v2) {
            atomicAdd(&lhist[d2.x >> 9], 1);
            atomicAdd(&lhist[d2.y >> 9], 1);
            atomicAdd(&lhist[d2.z >> 9], 1);
            atomicAdd(&lhist[d2.w >> 9], 1);
        }
        __syncthreads();
        {
            int c = lhist[tid];
            if (c) lbase[tid] = atomicAdd(&gcursor[tid], c);
            lhist[tid] = 0;
        }
        __syncthreads();
        if (v1) {
            int bin, r;
            bin = d1.x >> 9; r = atomicAdd(&lhist[bin], 1); pairs[lbase[bin] + r] = make_int2(s1.x, d1.x);
            bin = d1.y >> 9; r = atomicAdd(&lhist[bin], 1); pairs[lbase[bin] + r] = make_int2(s1.y, d1.y);
            bin = d1.z >> 9; r = atomicAdd(&lhist[bin], 1); pairs[lbase[bin] + r] = make_int2(s1.z, d1.z);
            bin = d1.w >> 9; r = atomicAdd(&lhist[bin], 1); pairs[lbase[bin] + r] = make_int2(s1.w, d1.w);
        }
        if (v2) {
            int bin, r;
            bin = d2.x >> 9; r = atomicAdd(&lhist[bin], 1); pairs[lbase[bin] + r] = make_int2(s2.x, d2.x);
            bin = d2.y >> 9; r = atomicAdd(&lhist[bin], 1); pairs[lbase[bin] + r] = make_int2(s2.y, d2.y);
            bin = d2.z >> 9; r = atomicAdd(&lhist[bin], 1); pairs[lbase[bin] + r] = make_int2(s2.z, d2.z);
            bin = d2.w >> 9; r = atomicAdd(&lhist[bin], 1); pairs[lbase[bin] + r] = make_int2(s2.w, d2.w);
        }
        return;
    }

    const int lane = tid & 63;
    const int w    = tid >> 6;             // wave id in block
    const int lm = lane & 15;              // x row (n) / W channel (m) in tile
    const int lk = lane >> 4;              // k-group / channel-quad selector
    const int row = (blockIdx.x - BUCKET_BLOCKS) * 64 + w * 16 + lm;
    const int rc  = row < NN ? row : NN - 1;

    // x fragment loads first (HBM, longest latency): 8 independent dwordx4.
    const float* xrow = x + (size_t)rc * CH;
    float4 xr[8];
    #pragma unroll
    for (int ks = 0; ks < 4; ++ks) {
        const float4* p = reinterpret_cast<const float4*>(xrow + ks * 32 + lk * 8);
        xr[ks * 2]     = p[0];
        xr[ks * 2 + 1] = p[1];
    }

    // Async W staging: 2048 granules of 16B.
    const bf16x8* Wb8 = reinterpret_cast<const bf16x8*>(Wb);
    #pragma unroll
    for (int it = 0; it < 8; ++it) {
        async_copy16(Wb8 + it * 256 + tid,
                     (char*)wlds + (size_t)(it * 256 + w * 64) * 16);
    }

    // Convert x to bf16 fragments while DMAs fly.
    bf16x8 bfrag[4];
    #pragma unroll
    for (int ks = 0; ks < 4; ++ks) {
        float4 u = xr[ks * 2], v = xr[ks * 2 + 1];
        bfrag[ks][0] = (__bf16)u.x; bfrag[ks][1] = (__bf16)u.y;
        bfrag[ks][2] = (__bf16)u.z; bfrag[ks][3] = (__bf16)u.w;
        bfrag[ks][4] = (__bf16)v.x; bfrag[ks][5] = (__bf16)v.y;
        bfrag[ks][6] = (__bf16)v.z; bfrag[ks][7] = (__bf16)v.w;
    }

    __syncthreads();   // drains vmcnt (x loads + LDS DMAs)

    const float4* B4 = reinterpret_cast<const float4*>(b);
    const int swz = (lm & 7) << 3;

    #pragma unroll
    for (int t = 0; t < 8; ++t) {
        const int ch = t * 16 + lm;
        float4 bv = B4[t * 4 + lk];
        f32x4 acc = {bv.x, bv.y, bv.z, bv.w};
        #pragma unroll
        for (int ks = 0; ks < 4; ++ks) {
            bf16x8 afrag = *reinterpret_cast<const bf16x8*>(
                &wlds[ch * 128 + ((ks * 32 + lk * 8) ^ swz)]);
            acc = __builtin_amdgcn_mfma_f32_16x16x32_bf16(afrag, bfrag[ks], acc, 0, 0, 0);
        }
        if (row < NN) {
            const int c0 = t * 16 + lk * 4;
            bf16x4 hv = {(__bf16)acc[0], (__bf16)acc[1], (__bf16)acc[2], (__bf16)acc[3]};
            *reinterpret_cast<bf16x4*>(&xt[(size_t)row * CH + c0]) = hv;
        }
    }
}

// ---- phase 2: per-bucket LDS counting sort -> dense srcs + offs ----
__global__ __launch_bounds__(256) void place2_kernel(
    const int* __restrict__ gcursor, const int2* __restrict__ pairs,
    int* __restrict__ srcs, int* __restrict__ offs)
{
    __shared__ int cntb[256];      // bucket counts -> scan -> dense bases
    __shared__ int cnt512[512];
    __shared__ int pref[512];      // prefix, then reused as cursor
    __shared__ int dense_base;
    const int tid = threadIdx.x;
    const int bkt = blockIdx.x;

    int c = gcursor[tid] - tid * CAP;     // 0 for unused bins
    cntb[tid] = c;
    __syncthreads();
    for (int off = 1; off < 256; off <<= 1) {
        int u = (tid >= off) ? cntb[tid - off] : 0;
        __syncthreads();
        cntb[tid] += u;
        __syncthreads();
    }
    if (tid == bkt) dense_base = cntb[tid] - c;        // exclusive prefix
    if (bkt == 0 && tid == 255) offs[NN] = cntb[255];  // == NE
    __syncthreads();

    const int n = gcursor[bkt] - bkt * CAP;
    const int2* P = pairs + (size_t)bkt * CAP;

    cnt512[tid] = 0; cnt512[tid + 256] = 0;
    __syncthreads();
    for (int i = tid; i < n; i += 256)
        atomicAdd(&cnt512[P[i].y & 511], 1);
    __syncthreads();

    int c0 = cnt512[2 * tid], c1 = cnt512[2 * tid + 1];
    int ps = c0 + c1;
    cntb[tid] = ps;
    __syncthreads();
    for (int off = 1; off < 256; off <<= 1) {
        int u = (tid >= off) ? cntb[tid - off] : 0;
        __syncthreads();
        cntb[tid] += u;
        __syncthreads();
    }
    int ex = cntb[tid] - ps;
    pref[2 * tid] = ex;
    pref[2 * tid + 1] = ex + c0;

    {
        int d0 = bkt * 512 + 2 * tid;
        if (d0 < NN)     offs[d0]     = dense_base + ex;
        if (d0 + 1 < NN) offs[d0 + 1] = dense_base + ex + c0;
    }
    __syncthreads();

    for (int i = tid; i < n; i += 256) {
        int2 p = P[i];
        int pos = atomicAdd(&pref[p.y & 511], 1);
        srcs[dense_base + pos] = p.x;
    }
}

// ---- gather-reduce: one node per QUARTER-wave; 4 loads in flight ----
__global__ __launch_bounds__(256) void gather_kernel(
    const uint4* __restrict__ xtu4,        // xt rows: [NN][16] uint4 (8 bf16)
    const int* __restrict__ offs, const int* __restrict__ srcs,
    float* __restrict__ out)
{
    const int gid  = blockIdx.x * 256 + threadIdx.x;
    const int lane = threadIdx.x & 63;
    const int q    = lane >> 4;            // quarter 0..3
    const int l16  = lane & 15;
    const int node = ((gid >> 6) << 2) + q;
    const int nd   = node < NN ? node : NN - 1;

    uint4 own = xtu4[(size_t)nd * 16 + l16];        // residual
    float a0 = bflo(own.x), a1 = bfhi(own.x);
    float a2 = bflo(own.y), a3 = bfhi(own.y);
    float a4 = bflo(own.z), a5 = bfhi(own.z);
    float a6 = bflo(own.w), a7 = bfhi(own.w);

    int beg = offs[nd];
    const int end = offs[nd + 1];
    const int qb  = q << 4;

    while (beg < end) {
        const int n = min(end - beg, 16);
        const int myidx = (l16 < n) ? srcs[beg + l16] : 0;
        for (int k = 0; k < n; k += 4) {
            // clamped indices: all 4 loads always issue (max MLP), adds predicated
            int k1 = min(k + 1, n - 1), k2 = min(k + 2, n - 1), k3 = min(k + 3, n - 1);
            int s0 = __shfl(myidx, qb + k);
            int s1 = __shfl(myidx, qb + k1);
            int s2 = __shfl(myidx, qb + k2);
            int s3 = __shfl(myidx, qb + k3);
            uint4 h0 = xtu4[(size_t)s0 * 16 + l16];
            uint4 h1 = xtu4[(size_t)s1 * 16 + l16];
            uint4 h2 = xtu4[(size_t)s2 * 16 + l16];
            uint4 h3 = xtu4[(size_t)s3 * 16 + l16];
            a0 += bflo(h0.x); a1 += bfhi(h0.x);
            a2 += bflo(h0.y); a3 += bfhi(h0.y);
            a4 += bflo(h0.z); a5 += bfhi(h0.z);
            a6 += bflo(h0.w); a7 += bfhi(h0.w);
            if (k + 1 < n) {
                a0 += bflo(h1.x); a1 += bfhi(h1.x);
                a2 += bflo(h1.y); a3 += bfhi(h1.y);
                a4 += bflo(h1.z); a5 += bfhi(h1.z);
                a6 += bflo(h1.w); a7 += bfhi(h1.w);
            }
            if (k + 2 < n) {
                a0 += bflo(h2.x); a1 += bfhi(h2.x);
                a2 += bflo(h2.y); a3 += bfhi(h2.y);
                a4 += bflo(h2.z); a5 += bfhi(h2.z);
                a6 += bflo(h2.w); a7 += bfhi(h2.w);
            }
            if (k + 3 < n) {
                a0 += bflo(h3.x); a1 += bfhi(h3.x);
                a2 += bflo(h3.y); a3 += bfhi(h3.y);
                a4 += bflo(h3.z); a5 += bfhi(h3.z);
                a6 += bflo(h3.w); a7 += bfhi(h3.w);
            }
        }
        beg += n;
    }

    if (node < NN) {
        float4* o4 = reinterpret_cast<float4*>(out) + (size_t)node * 32 + l16 * 2;
        o4[0] = make_float4(a0, a1, a2, a3);
        o4[1] = make_float4(a4, a5, a6, a7);
    }
}

extern "C" void kernel_launch(void* const* d_in, const int* in_sizes, int n_in,
                              void* d_out, int out_size, void* d_ws, size_t ws_size,
                              hipStream_t stream) {
    const float* x  = (const float*)d_in[0];
    const int*   ei = (const int*)d_in[1];   // [2][NE] int32
    const float* W  = (const float*)d_in[2];
    const float* b  = (const float*)d_in[3];
    float* out = (float*)d_out;

    __bf16* xt     = (__bf16*)d_ws;                       // 25.6 MB
    int2*   pairs  = (int2*)(xt + (size_t)NN * CH);       // 256*CAP*8B = 8 MB
    int*    srcs   = (int*)(pairs + (size_t)256 * CAP);   // NE = 2.5 MB
    int*    offs   = srcs + NE;                           // NN+1
    int*    gcur   = offs + NN + 1;                       // 256
    __bf16* Wb     = (__bf16*)(gcur + 256);               // 32 KB

    prep_kernel<<<1 + WCONV_BLOCKS, 256, 0, stream>>>(gcur, W, Wb);
    gemm_bucket_kernel<<<BUCKET_BLOCKS + GEMM_BLOCKS, 256, 0, stream>>>(
        x, Wb, b, xt, ei, gcur, pairs);
    place2_kernel<<<NB, 256, 0, stream>>>(gcur, pairs, srcs, offs);
    const int gwaves = (NN + 3) / 4;   // 4 nodes per wave
    gather_kernel<<<(gwaves * 64 + 255) / 256, 256, 0, stream>>>(
        (const uint4*)xt, offs, srcs, out);
}

// Round 19
// 82.221 us; speedup vs baseline: 1.0891x; 1.0891x over previous
//
#include <hip/hip_runtime.h>

constexpr int NN = 100000;
constexpr int CH = 128;
constexpr int NE = 625000;
constexpr int GEMM_BLOCKS = (NN + 127) / 128;      // 782 (128 rows/block, 8 waves x 16)
constexpr int BUCKET_BLOCKS = 256;                 // phase-1 bucketing blocks
constexpr int EDGES_PER_BLOCK = (NE + BUCKET_BLOCKS - 1) / BUCKET_BLOCKS;  // 2442
constexpr int NB = 196;                            // ceil(NN/512) coarse buckets
constexpr int CAP = 4096;                          // slots/bucket (max ~3390)
constexpr int WCONV_BLOCKS = 16;                   // 16384 elems / 1024

typedef __bf16 bf16x8 __attribute__((ext_vector_type(8)));
typedef __bf16 bf16x4 __attribute__((ext_vector_type(4)));
typedef float  f32x4  __attribute__((ext_vector_type(4)));

__device__ __forceinline__ float bflo(uint u) { return __uint_as_float(u << 16); }
__device__ __forceinline__ float bfhi(uint u) { return __uint_as_float(u & 0xffff0000u); }

// Async 16B global->LDS DMA. LDS dest is wave-uniform base + lane*16.
__device__ __forceinline__ void async_copy16(const void* g, void* l) {
    __builtin_amdgcn_global_load_lds(
        (const __attribute__((address_space(1))) unsigned int*)(uintptr_t)g,
        (__attribute__((address_space(3))) unsigned int*)(uintptr_t)l,
        16, 0, 0);
}

// ---- prep: init bucket cursors + convert W to bf16 swizzled ----
__global__ __launch_bounds__(256) void prep_kernel(
    int* __restrict__ gcursor, const float* __restrict__ W, __bf16* __restrict__ Wb)
{
    if (blockIdx.x == 0) {
        gcursor[threadIdx.x] = threadIdx.x * CAP;
        return;
    }
    int i = (blockIdx.x - 1) * 256 + threadIdx.x;   // float4 group, 4096 total
    int ch = i >> 5;
    int k0 = (i & 31) * 4;
    float4 v = reinterpret_cast<const float4*>(W)[i];
    bf16x4 h = {(__bf16)v.x, (__bf16)v.y, (__bf16)v.z, (__bf16)v.w};
    *reinterpret_cast<bf16x4*>(&Wb[ch * 128 + (k0 ^ ((ch & 7) << 3))]) = h;
}

// ---- fused: coarse bucketing (blocks < BUCKET_BLOCKS) + MFMA GEMM ----
// 512 threads/block. GEMM: 8 waves share one 32KB W stage (128 rows/block);
// 4 blocks/CU x 8 waves = 32 waves/CU (full slots). Bucket: r16 structure
// at stride 512; per-edge atomics LDS-only.
__global__ __launch_bounds__(512) void gemm_bucket_kernel(
    const float* __restrict__ x, const __bf16* __restrict__ Wb,
    const float* __restrict__ b, __bf16* __restrict__ xt,
    const int* __restrict__ ei, int* __restrict__ gcursor, int2* __restrict__ pairs)
{
    __shared__ __bf16 wlds[128 * 128];     // 32 KB; bucket blocks alias it
    const int tid = threadIdx.x;

    if (blockIdx.x < BUCKET_BLOCKS) {
        int* lhist = (int*)wlds;           // [256]
        int* lbase = lhist + 256;          // [256]
        const int e0 = blockIdx.x * EDGES_PER_BLOCK;
        const int myN = min(NE - e0, EDGES_PER_BLOCK);
        if (tid < 256) lhist[tid] = 0;
        __syncthreads();
        for (int i = tid; i < myN; i += 512) {
            int dst = ei[NE + e0 + i];
            atomicAdd(&lhist[dst >> 9], 1);
        }
        __syncthreads();
        if (tid < 256) {
            int c = lhist[tid];
            if (c) lbase[tid] = atomicAdd(&gcursor[tid], c);
            lhist[tid] = 0;
        }
        __syncthreads();
        for (int i = tid; i < myN; i += 512) {
            int src = ei[e0 + i];
            int dst = ei[NE + e0 + i];
            int bin = dst >> 9;
            int r = atomicAdd(&lhist[bin], 1);
            pairs[lbase[bin] + r] = make_int2(src, dst);
        }
        return;
    }

    const int lane = tid & 63;
    const int w    = tid >> 6;             // wave id 0..7
    const int lm = lane & 15;              // x row (n) / W channel (m) in tile
    const int lk = lane >> 4;              // k-group / channel-quad selector
    const int row = (blockIdx.x - BUCKET_BLOCKS) * 128 + w * 16 + lm;
    const int rc  = row < NN ? row : NN - 1;

    // x fragment loads first (HBM, longest latency): 8 independent dwordx4.
    const float* xrow = x + (size_t)rc * CH;
    float4 xr[8];
    #pragma unroll
    for (int ks = 0; ks < 4; ++ks) {
        const float4* p = reinterpret_cast<const float4*>(xrow + ks * 32 + lk * 8);
        xr[ks * 2]     = p[0];
        xr[ks * 2 + 1] = p[1];
    }

    // Async W staging: 2048 granules of 16B over 512 threads = 4 issues.
    const bf16x8* Wb8 = reinterpret_cast<const bf16x8*>(Wb);
    #pragma unroll
    for (int it = 0; it < 4; ++it) {
        async_copy16(Wb8 + it * 512 + tid,
                     (char*)wlds + (size_t)(it * 512 + w * 64) * 16);
    }

    // Convert x to bf16 fragments while DMAs fly.
    bf16x8 bfrag[4];
    #pragma unroll
    for (int ks = 0; ks < 4; ++ks) {
        float4 u = xr[ks * 2], v = xr[ks * 2 + 1];
        bfrag[ks][0] = (__bf16)u.x; bfrag[ks][1] = (__bf16)u.y;
        bfrag[ks][2] = (__bf16)u.z; bfrag[ks][3] = (__bf16)u.w;
        bfrag[ks][4] = (__bf16)v.x; bfrag[ks][5] = (__bf16)v.y;
        bfrag[ks][6] = (__bf16)v.z; bfrag[ks][7] = (__bf16)v.w;
    }

    __syncthreads();   // drains vmcnt (x loads + LDS DMAs)

    const float4* B4 = reinterpret_cast<const float4*>(b);
    const int swz = (lm & 7) << 3;

    #pragma unroll
    for (int t = 0; t < 8; ++t) {
        const int ch = t * 16 + lm;
        float4 bv = B4[t * 4 + lk];
        f32x4 acc = {bv.x, bv.y, bv.z, bv.w};
        #pragma unroll
        for (int ks = 0; ks < 4; ++ks) {
            bf16x8 afrag = *reinterpret_cast<const bf16x8*>(
                &wlds[ch * 128 + ((ks * 32 + lk * 8) ^ swz)]);
            acc = __builtin_amdgcn_mfma_f32_16x16x32_bf16(afrag, bfrag[ks], acc, 0, 0, 0);
        }
        if (row < NN) {
            const int c0 = t * 16 + lk * 4;
            bf16x4 hv = {(__bf16)acc[0], (__bf16)acc[1], (__bf16)acc[2], (__bf16)acc[3]};
            *reinterpret_cast<bf16x4*>(&xt[(size_t)row * CH + c0]) = hv;
        }
    }
}

// ---- phase 2: per-bucket LDS counting sort -> dense srcs + offs ----
__global__ __launch_bounds__(256) void place2_kernel(
    const int* __restrict__ gcursor, const int2* __restrict__ pairs,
    int* __restrict__ srcs, int* __restrict__ offs)
{
    __shared__ int cntb[256];      // bucket counts -> scan -> dense bases
    __shared__ int cnt512[512];
    __shared__ int pref[512];      // prefix, then reused as cursor
    __shared__ int dense_base;
    const int tid = threadIdx.x;
    const int bkt = blockIdx.x;

    int c = gcursor[tid] - tid * CAP;     // 0 for unused bins
    cntb[tid] = c;
    __syncthreads();
    for (int off = 1; off < 256; off <<= 1) {
        int u = (tid >= off) ? cntb[tid - off] : 0;
        __syncthreads();
        cntb[tid] += u;
        __syncthreads();
    }
    if (tid == bkt) dense_base = cntb[tid] - c;        // exclusive prefix
    if (bkt == 0 && tid == 255) offs[NN] = cntb[255];  // == NE
    __syncthreads();

    const int n = gcursor[bkt] - bkt * CAP;
    const int2* P = pairs + (size_t)bkt * CAP;

    cnt512[tid] = 0; cnt512[tid + 256] = 0;
    __syncthreads();
    for (int i = tid; i < n; i += 256)
        atomicAdd(&cnt512[P[i].y & 511], 1);
    __syncthreads();

    int c0 = cnt512[2 * tid], c1 = cnt512[2 * tid + 1];
    int ps = c0 + c1;
    cntb[tid] = ps;
    __syncthreads();
    for (int off = 1; off < 256; off <<= 1) {
        int u = (tid >= off) ? cntb[tid - off] : 0;
        __syncthreads();
        cntb[tid] += u;
        __syncthreads();
    }
    int ex = cntb[tid] - ps;
    pref[2 * tid] = ex;
    pref[2 * tid + 1] = ex + c0;

    {
        int d0 = bkt * 512 + 2 * tid;
        if (d0 < NN)     offs[d0]     = dense_base + ex;
        if (d0 + 1 < NN) offs[d0 + 1] = dense_base + ex + c0;
    }
    __syncthreads();

    for (int i = tid; i < n; i += 256) {
        int2 p = P[i];
        int pos = atomicAdd(&pref[p.y & 511], 1);
        srcs[dense_base + pos] = p.x;
    }
}

// ---- gather-reduce: one node per QUARTER-wave (r16 winner, unroll-2) ----
__global__ __launch_bounds__(256) void gather_kernel(
    const uint4* __restrict__ xtu4,        // xt rows: [NN][16] uint4 (8 bf16)
    const int* __restrict__ offs, const int* __restrict__ srcs,
    float* __restrict__ out)
{
    const int gid  = blockIdx.x * 256 + threadIdx.x;
    const int lane = threadIdx.x & 63;
    const int q    = lane >> 4;            // quarter 0..3
    const int l16  = lane & 15;
    const int node = ((gid >> 6) << 2) + q;
    const int nd   = node < NN ? node : NN - 1;

    uint4 own = xtu4[(size_t)nd * 16 + l16];        // residual
    float a0 = bflo(own.x), a1 = bfhi(own.x);
    float a2 = bflo(own.y), a3 = bfhi(own.y);
    float a4 = bflo(own.z), a5 = bfhi(own.z);
    float a6 = bflo(own.w), a7 = bfhi(own.w);

    int beg = offs[nd];
    const int end = offs[nd + 1];

    while (beg < end) {
        const int n = min(end - beg, 16);
        const int myidx = (l16 < n) ? srcs[beg + l16] : 0;
        int k = 0;
        for (; k + 1 < n; k += 2) {                 // 2 loads in flight
            int s0 = __shfl(myidx, (q << 4) + k);
            int s1 = __shfl(myidx, (q << 4) + k + 1);
            uint4 h0 = xtu4[(size_t)s0 * 16 + l16];
            uint4 h1 = xtu4[(size_t)s1 * 16 + l16];
            a0 += bflo(h0.x); a1 += bfhi(h0.x);
            a2 += bflo(h0.y); a3 += bfhi(h0.y);
            a4 += bflo(h0.z); a5 += bfhi(h0.z);
            a6 += bflo(h0.w); a7 += bfhi(h0.w);
            a0 += bflo(h1.x); a1 += bfhi(h1.x);
            a2 += bflo(h1.y); a3 += bfhi(h1.y);
            a4 += bflo(h1.z); a5 += bfhi(h1.z);
            a6 += bflo(h1.w); a7 += bfhi(h1.w);
        }
        if (k < n) {
            int s0 = __shfl(myidx, (q << 4) + k);
            uint4 h0 = xtu4[(size_t)s0 * 16 + l16];
            a0 += bflo(h0.x); a1 += bfhi(h0.x);
            a2 += bflo(h0.y); a3 += bfhi(h0.y);
            a4 += bflo(h0.z); a5 += bfhi(h0.z);
            a6 += bflo(h0.w); a7 += bfhi(h0.w);
        }
        beg += n;
    }

    if (node < NN) {
        float4* o4 = reinterpret_cast<float4*>(out) + (size_t)node * 32 + l16 * 2;
        o4[0] = make_float4(a0, a1, a2, a3);
        o4[1] = make_float4(a4, a5, a6, a7);
    }
}

extern "C" void kernel_launch(void* const* d_in, const int* in_sizes, int n_in,
                              void* d_out, int out_size, void* d_ws, size_t ws_size,
                              hipStream_t stream) {
    const float* x  = (const float*)d_in[0];
    const int*   ei = (const int*)d_in[1];   // [2][NE] int32
    const float* W  = (const float*)d_in[2];
    const float* b  = (const float*)d_in[3];
    float* out = (float*)d_out;

    __bf16* xt     = (__bf16*)d_ws;                       // 25.6 MB
    int2*   pairs  = (int2*)(xt + (size_t)NN * CH);       // 256*CAP*8B = 8 MB
    int*    srcs   = (int*)(pairs + (size_t)256 * CAP);   // NE = 2.5 MB
    int*    offs   = srcs + NE;                           // NN+1
    int*    gcur   = offs + NN + 1;                       // 256
    __bf16* Wb     = (__bf16*)(gcur + 256);               // 32 KB

    prep_kernel<<<1 + WCONV_BLOCKS, 256, 0, stream>>>(gcur, W, Wb);
    gemm_bucket_kernel<<<BUCKET_BLOCKS + GEMM_BLOCKS, 512, 0, stream>>>(
        x, Wb, b, xt, ei, gcur, pairs);
    place2_kernel<<<NB, 256, 0, stream>>>(gcur, pairs, srcs, offs);
    const int gwaves = (NN + 3) / 4;   // 4 nodes per wave
    gather_kernel<<<(gwaves * 64 + 255) / 256, 256, 0, stream>>>(
        (const uint4*)xt, offs, srcs, out);
}